// Round 14
// baseline (176.442 us; speedup 1.0000x reference)
//
#include <hip/hip_runtime.h>
#include <stdint.h>

#define B_ 128
#define N_ 512
#define I_ 256
#define M_ 32
#define D_ 16

typedef __attribute__((ext_vector_type(4))) float f32x4;
typedef __attribute__((ext_vector_type(4))) float float4v;
typedef __attribute__((ext_vector_type(8))) short short8;     // 8 bf16 MFMA frag
typedef __attribute__((ext_vector_type(4))) unsigned int u32x4;
typedef __attribute__((ext_vector_type(4))) unsigned short ushort4v;
typedef unsigned short ushort;

__device__ __forceinline__ float bf2f(ushort u) {
    union { unsigned int i; float f; } v; v.i = ((unsigned int)u) << 16; return v.f;
}
__device__ __forceinline__ ushort f2bf(float f) {
    union { float f; unsigned int i; } v; v.f = f;
    unsigned int r = v.i + 0x7FFFu + ((v.i >> 16) & 1u);   // RNE
    return (ushort)(r >> 16);
}

__device__ __forceinline__ short8 cvt8(float4v lo, float4v hi) {
    unsigned int u0, u1, u2, u3;
    asm("v_cvt_pk_bf16_f32 %0, %1, %2" : "=v"(u0) : "v"(lo[0]), "v"(lo[1]));
    asm("v_cvt_pk_bf16_f32 %0, %1, %2" : "=v"(u1) : "v"(lo[2]), "v"(lo[3]));
    asm("v_cvt_pk_bf16_f32 %0, %1, %2" : "=v"(u2) : "v"(hi[0]), "v"(hi[1]));
    asm("v_cvt_pk_bf16_f32 %0, %1, %2" : "=v"(u3) : "v"(hi[2]), "v"(hi[3]));
    u32x4 uv = {u0, u1, u2, u3};
    return __builtin_bit_cast(short8, uv);
}

// volatile asm 16B load with compile-time byte offset; cannot be sunk/split.
#define GL16(dst, base, imm) \
    asm volatile("global_load_dwordx4 %0, %1, off offset:%2" \
                 : "=&v"(dst) : "v"(base), "n"(imm))

#define VMW(nn) do { \
    asm volatile("s_waitcnt vmcnt(" #nn ")" ::: "memory"); \
    __builtin_amdgcn_sched_barrier(0); \
} while (0)

#define SBAR() __builtin_amdgcn_sched_barrier(0)

#define LGKM0_BARRIER() do { \
    asm volatile("s_waitcnt lgkmcnt(0)" ::: "memory"); \
    __builtin_amdgcn_sched_barrier(0); \
    __builtin_amdgcn_s_barrier(); \
    __builtin_amdgcn_sched_barrier(0); \
} while (0)

// -----------------------------------------------------------------------------
// Kernel 1: inputs_hat[b,m,n,d] = sum_i x[b,n,i] * W[m,n,d,i]
// r13 traffic-minimal structure + FIFO reordering (r13 lesson: vmcnt FIFO is
// shared with stores; in-order retirement means loads issued BEFORE stores
// never wait on them). Changes:
//  (1) next-m's 4 load-groups issued BEFORE the epilogue stores
//      -> steps 0-3 wait VMW(38) (= 6 loads + 32 stores behind the target);
//  (2) m0's groups issued before the stage LDS-write + raw lgkmcnt-only
//      barrier (no vmcnt(0) drain at the stage boundary).
// -----------------------------------------------------------------------------
__global__ __launch_bounds__(512, 4) void hat_gemm(const float* __restrict__ x,
                                                   const float* __restrict__ W,
                                                   ushort* __restrict__ hat) {
    __shared__ ushort As[128 * 256];    // 64 KB; granule g of row r at g^(r&15)

    const int bid = blockIdx.x;         // 0..511
    const int n   = (bid & 7) * 64 + (bid >> 3);   // XCD-chunked n

    const int tid  = threadIdx.x;       // 0..511
    const int lane = tid & 63;
    const int w    = tid >> 6;          // wave 0..7
    const int l15  = lane & 15;
    const int kq   = lane >> 4;         // 0..3

    const size_t mstride = (size_t)N_ * D_ * I_;   // W floats per m
    const float* wm = W + (((size_t)(w * 4) * N_ + n) * D_ + l15) * I_ + kq * 8;

    float4v L0, H0, L1, H1, L2, H2, L3, H3;

    // ---- stage x[.][n] -> bf16 LDS; W groups for m0 issued before barrier ----
    {
        const int row = tid >> 2;       // b = 0..127
        const int seg = tid & 3;        // 64 floats each
        const float* xp = x + ((size_t)row * N_ + n) * I_ + seg * 64;
        float4v sv[16];
        #pragma unroll
        for (int j = 0; j < 16; ++j) GL16(sv[j], xp, j * 16);
        // m0 W groups 0..3 (stay in flight across cvt + barrier)
        GL16(L0, wm, 0);   GL16(H0, wm, 16);
        GL16(L1, wm, 128); GL16(H1, wm, 144);
        GL16(L2, wm, 256); GL16(H2, wm, 272);
        GL16(L3, wm, 384); GL16(H3, wm, 400);
        VMW(8);            // x loads (oldest 16) retired; 8 W loads remain
        #pragma unroll
        for (int i = 0; i < 8; ++i) {
            short8 h = cvt8(sv[2 * i], sv[2 * i + 1]);
            const int gsw = ((seg * 8 + i) ^ (row & 15));
            *(short8*)&As[row * 256 + gsw * 8] = h;
        }
    }
    LGKM0_BARRIER();        // raw barrier: no vmcnt(0) drain of the W loads

    const int abase = l15 * 256;        // A-frag: + a*4096 + gsw*8

    #define MF(bb, ks) do { \
        const int gsw_ = (((ks) * 4 + kq) ^ l15) * 8; \
        _Pragma("unroll") \
        for (int a = 0; a < 8; ++a) { \
            short8 af = *(const short8*)&As[abase + a * 4096 + gsw_]; \
            acc[a] = __builtin_amdgcn_mfma_f32_16x16x32_bf16(af, (bb), acc[a], 0, 0, 0); \
        } \
    } while (0)

    // ---- main: wave w handles m = w*4 + mq; FIFO per m: [G0..G3][S32] ----
    #pragma unroll
    for (int mq = 0; mq < 4; ++mq) {
        const int m = w * 4 + mq;

        f32x4 acc[8];
        #pragma unroll
        for (int a = 0; a < 8; ++a) { f32x4 z = {0.f, 0.f, 0.f, 0.f}; acc[a] = z; }

        // steps 0-3: wait group, reuse regs for group ks+4
        if (mq == 0) {
            VMW(6);  { short8 bb = cvt8(L0, H0); GL16(L0, wm, 512); GL16(H0, wm, 528); MF(bb, 0); }
            VMW(6);  { short8 bb = cvt8(L1, H1); GL16(L1, wm, 640); GL16(H1, wm, 656); MF(bb, 1); }
            VMW(6);  { short8 bb = cvt8(L2, H2); GL16(L2, wm, 768); GL16(H2, wm, 784); MF(bb, 2); }
            VMW(6);  { short8 bb = cvt8(L3, H3); GL16(L3, wm, 896); GL16(H3, wm, 912); MF(bb, 3); }
        } else {
            // 32 stores of m-1 sit between G0..G3 and G4..G7: 38 = 6 + 32
            VMW(38); { short8 bb = cvt8(L0, H0); GL16(L0, wm, 512); GL16(H0, wm, 528); MF(bb, 0); }
            VMW(38); { short8 bb = cvt8(L1, H1); GL16(L1, wm, 640); GL16(H1, wm, 656); MF(bb, 1); }
            VMW(38); { short8 bb = cvt8(L2, H2); GL16(L2, wm, 768); GL16(H2, wm, 784); MF(bb, 2); }
            VMW(38); { short8 bb = cvt8(L3, H3); GL16(L3, wm, 896); GL16(H3, wm, 912); MF(bb, 3); }
        }
        // steps 4-7: tail (stores of m-1 are older than G4: drained by now)
        VMW(6);  { short8 bb = cvt8(L0, H0); MF(bb, 4); }
        VMW(4);  { short8 bb = cvt8(L1, H1); MF(bb, 5); }
        VMW(2);  { short8 bb = cvt8(L2, H2); MF(bb, 6); }
        VMW(0);  { short8 bb = cvt8(L3, H3); MF(bb, 7); }

        // epilogue: issue NEXT m's groups 0..3 FIRST, then this m's stores
        if (mq < 3) {
            wm += mstride;
            GL16(L0, wm, 0);   GL16(H0, wm, 16);
            GL16(L1, wm, 128); GL16(H1, wm, 144);
            GL16(L2, wm, 256); GL16(H2, wm, 272);
            GL16(L3, wm, 384); GL16(H3, wm, 400);
            SBAR();   // stores below may not hoist above these loads
        }
        #pragma unroll
        for (int a = 0; a < 8; ++a) {
            #pragma unroll
            for (int r = 0; r < 4; ++r) {
                const int brow = a * 16 + kq * 4 + r;
                const size_t idx = (((size_t)brow * M_ + m) * N_ + n) * D_ + l15;
                hat[idx] = f2bf(acc[a][r]);
            }
        }
        SBAR();
    }
    #undef MF
    VMW(0);   // flush stores before endpgm
}

// -----------------------------------------------------------------------------
// Kernel 2: dynamic routing, FUSED: 3 hat passes instead of 5.
// Pass 1: s0 with c = 1/32 (softmax of zeros). Transitions t=0,1: one hat
// read serves BOTH the b-logit dot-update and the next iteration's c*hat
// accumulation (hat frags held in regs across one barrier; per-n softmax
// makes the fusion bitwise exact vs the unfused version).
// -----------------------------------------------------------------------------
__global__ __launch_bounds__(512, 1) void routing(const ushort* __restrict__ hat,
                                                  float* __restrict__ out) {
    __shared__ float blog[M_][N_];      // 64 KB

    const int b    = blockIdx.x;
    const int tid  = threadIdx.x;
    const int lane = tid & 63;
    const int w    = tid >> 6;

    #pragma unroll
    for (int m = 0; m < M_; ++m) blog[m][tid] = 0.f;
    __syncthreads();

    float ov[4][16], sacc[4][16];

    #define REDUCE_SQUASH() do { \
        _Pragma("unroll") \
        for (int off = 32; off >= 1; off >>= 1) { \
            _Pragma("unroll") \
            for (int q = 0; q < 4; ++q) \
                _Pragma("unroll") \
                for (int dd = 0; dd < 16; ++dd) \
                    sacc[q][dd] += __shfl_xor(sacc[q][dd], off, 64); \
        } \
        _Pragma("unroll") \
        for (int q = 0; q < 4; ++q) { \
            float s2 = 0.f; \
            _Pragma("unroll") \
            for (int dd = 0; dd < 16; ++dd) s2 += sacc[q][dd] * sacc[q][dd]; \
            const float scale = s2 / (1.f + s2) / sqrtf(s2 + 1e-7f); \
            _Pragma("unroll") \
            for (int dd = 0; dd < 16; ++dd) ov[q][dd] = scale * sacc[q][dd]; \
        } \
    } while (0)

    // ---- pass 1: s0 = sum_n (1/32) * hat ----
    #pragma unroll
    for (int q = 0; q < 4; ++q)
        #pragma unroll
        for (int dd = 0; dd < 16; ++dd) sacc[q][dd] = 0.f;

    for (int r = 0; r < 8; ++r) {
        const int nn = r * 64 + lane;
        #pragma unroll
        for (int q = 0; q < 4; ++q) {
            const int m = w * 4 + q;
            const size_t base = (((size_t)b * M_ + m) * N_ + nn) * D_;
            short8 h0 = *(const short8*)(hat + base);
            short8 h1 = *(const short8*)(hat + base + 8);
            const float cm = 0.03125f;     // softmax(0) over 32
            #pragma unroll
            for (int dd = 0; dd < 8; ++dd) {
                sacc[q][dd]     += cm * bf2f((ushort)h0[dd]);
                sacc[q][8 + dd] += cm * bf2f((ushort)h1[dd]);
            }
        }
    }
    REDUCE_SQUASH();

    // ---- transitions t=0,1: fused dot->blog->softmax->s accumulation ----
    for (int t = 0; t < 2; ++t) {
        #pragma unroll
        for (int q = 0; q < 4; ++q)
            #pragma unroll
            for (int dd = 0; dd < 16; ++dd) sacc[q][dd] = 0.f;

        for (int r = 0; r < 8; ++r) {
            const int nn = r * 64 + lane;
            short8 hh0[4], hh1[4];
            #pragma unroll
            for (int q = 0; q < 4; ++q) {
                const int m = w * 4 + q;
                const size_t base = (((size_t)b * M_ + m) * N_ + nn) * D_;
                hh0[q] = *(const short8*)(hat + base);
                hh1[q] = *(const short8*)(hat + base + 8);
                float dot = 0.f;
                #pragma unroll
                for (int dd = 0; dd < 8; ++dd) {
                    dot += ov[q][dd]     * bf2f((ushort)hh0[q][dd]);
                    dot += ov[q][8 + dd] * bf2f((ushort)hh1[q][dd]);
                }
                blog[m][nn] += dot;        // owner-exclusive RMW
            }
            __syncthreads();               // all m's logits for these nn final
            float mx = -3.4e38f;
            #pragma unroll
            for (int mm = 0; mm < M_; ++mm) mx = fmaxf(mx, blog[mm][nn]);
            float ss = 0.f;
            #pragma unroll
            for (int mm = 0; mm < M_; ++mm) ss += __expf(blog[mm][nn] - mx);
            const float rs = 1.f / ss;
            #pragma unroll
            for (int q = 0; q < 4; ++q) {
                const float cm = __expf(blog[w * 4 + q][nn] - mx) * rs;
                #pragma unroll
                for (int dd = 0; dd < 8; ++dd) {
                    sacc[q][dd]     += cm * bf2f((ushort)hh0[q][dd]);
                    sacc[q][8 + dd] += cm * bf2f((ushort)hh1[q][dd]);
                }
            }
        }
        REDUCE_SQUASH();
    }
    #undef REDUCE_SQUASH

    // ---- write final outputs [B, M, D] fp32 ----
    if (lane == 0) {
        #pragma unroll
        for (int q = 0; q < 4; ++q) {
            const int m = w * 4 + q;
            #pragma unroll
            for (int c4 = 0; c4 < 4; ++c4) {
                float4v v;
                v[0] = ov[q][c4 * 4 + 0];
                v[1] = ov[q][c4 * 4 + 1];
                v[2] = ov[q][c4 * 4 + 2];
                v[3] = ov[q][c4 * 4 + 3];
                *(float4v*)&out[((size_t)b * M_ + m) * D_ + c4 * 4] = v;
            }
        }
    }
}

extern "C" void kernel_launch(void* const* d_in, const int* in_sizes, int n_in,
                              void* d_out, int out_size, void* d_ws, size_t ws_size,
                              hipStream_t stream) {
    const float* x = (const float*)d_in[0];        // [128, 512, 256] fp32
    const float* W = (const float*)d_in[1];        // [32, 512, 16, 256] fp32
    ushort* hat = (ushort*)d_ws;                   // bf16 [128,32,512,16] = 64 MB
    float* out = (float*)d_out;                    // fp32 [128,32,16]

    hat_gemm<<<dim3(N_), dim3(512), 0, stream>>>(x, W, hat);
    routing<<<dim3(B_), dim3(512), 0, stream>>>(hat, out);
}

// Round 16
// 161.255 us; speedup vs baseline: 1.0942x; 1.0942x over previous
//
#include <hip/hip_runtime.h>
#include <stdint.h>

#define B_ 128
#define N_ 512
#define I_ 256
#define M_ 32
#define D_ 16

typedef __attribute__((ext_vector_type(4))) float f32x4;
typedef __attribute__((ext_vector_type(4))) float float4v;
typedef __attribute__((ext_vector_type(8))) short short8;     // 8 bf16 MFMA frag
typedef __attribute__((ext_vector_type(2))) unsigned int u32x2;
typedef __attribute__((ext_vector_type(4))) unsigned int u32x4;
typedef unsigned short ushort;

__device__ __forceinline__ float bf2f(ushort u) {
    union { unsigned int i; float f; } v; v.i = ((unsigned int)u) << 16; return v.f;
}
__device__ __forceinline__ ushort f2bf(float f) {
    union { float f; unsigned int i; } v; v.f = f;
    unsigned int r = v.i + 0x7FFFu + ((v.i >> 16) & 1u);   // RNE
    return (ushort)(r >> 16);
}

__device__ __forceinline__ short8 cvt8(float4v lo, float4v hi) {
    unsigned int u0, u1, u2, u3;
    asm("v_cvt_pk_bf16_f32 %0, %1, %2" : "=v"(u0) : "v"(lo[0]), "v"(lo[1]));
    asm("v_cvt_pk_bf16_f32 %0, %1, %2" : "=v"(u1) : "v"(lo[2]), "v"(lo[3]));
    asm("v_cvt_pk_bf16_f32 %0, %1, %2" : "=v"(u2) : "v"(hi[0]), "v"(hi[1]));
    asm("v_cvt_pk_bf16_f32 %0, %1, %2" : "=v"(u3) : "v"(hi[2]), "v"(hi[3]));
    u32x4 uv = {u0, u1, u2, u3};
    return __builtin_bit_cast(short8, uv);
}
__device__ __forceinline__ u32x2 cvt4(float4v v) {
    unsigned int u0, u1;
    asm("v_cvt_pk_bf16_f32 %0, %1, %2" : "=v"(u0) : "v"(v[0]), "v"(v[1]));
    asm("v_cvt_pk_bf16_f32 %0, %1, %2" : "=v"(u1) : "v"(v[2]), "v"(v[3]));
    u32x2 r = {u0, u1};
    return r;
}

// volatile asm 16B load with compile-time byte offset (r13-proven form).
// RULE (r15 crash lesson): a VMW0() MUST sit between issue and ANY consume of
// the destination registers — the compiler does not track asm loads.
#define GL16(dst, base, imm) \
    asm volatile("global_load_dwordx4 %0, %1, off offset:%2" \
                 : "=&v"(dst) : "v"(base), "n"(imm))

#define VMW0() do { \
    asm volatile("s_waitcnt vmcnt(0)" ::: "memory"); \
    __builtin_amdgcn_sched_barrier(0); \
} while (0)

// -----------------------------------------------------------------------------
// Kernel 1: inputs_hat[b,m,n,d] = sum_i x[b,n,i] * W[m,n,d,i]
// Coalescing-first structure (r14 analysis: BW ~ 1/runs-per-instruction).
// Block per n (512, XCD-chunked), 8 waves.
//  phase 1: x[.][n] -> bf16 LDS, r13-proven staging (16B/lane, granule swizzle
//           g^(row&15)).
//  phase 2: wave w copies its 16-row A-band (8 K-step frags) into 32 VGPRs.
//  phase 3: LDS reused as W double-buffer (2 x 32KB). 8 chunks of 4 m's; each
//           chunk = 64 contiguous 1KB W d-rows, loaded as ONE run per
//           instruction (64 lanes x 16B), cvt -> swizzled LDS, 32 MFMA/wave.
//           Chunk c+1 loads issued before compute(c); full drain after.
// -----------------------------------------------------------------------------
__global__ __launch_bounds__(512, 2) void hat_gemm(const float* __restrict__ x,
                                                   const float* __restrict__ W,
                                                   ushort* __restrict__ hat) {
    __shared__ ushort LDS[32768];   // 64 KB

    const int bid = blockIdx.x;     // 0..511
    const int n   = (bid & 7) * 64 + (bid >> 3);   // XCD-chunked n

    const int tid  = threadIdx.x;   // 0..511
    const int lane = tid & 63;
    const int w    = tid >> 6;      // wave 0..7; owns b-rows [w*16, w*16+16)
    const int l15  = lane & 15;
    const int kq   = lane >> 4;     // 0..3

    // ---- phase 1: stage x -> bf16 LDS (r13-proven pattern) ----
    {
        const int row = tid >> 2;       // b = 0..127
        const int seg = tid & 3;        // quarter-row (64 floats)
        const float* xp = x + ((size_t)row * N_ + n) * I_ + seg * 64;
        float4v sx[16];
        #pragma unroll
        for (int j = 0; j < 16; ++j) GL16(sx[j], xp, j * 16);
        VMW0();                          // loads landed before ANY consume
        #pragma unroll
        for (int i = 0; i < 8; ++i) {
            short8 h = cvt8(sx[2 * i], sx[2 * i + 1]);
            const int gsw = (seg * 8 + i) ^ (row & 15);
            *(short8*)&LDS[row * 256 + gsw * 8] = h;
        }
    }
    __syncthreads();

    // ---- phase 2: A-band into registers (row = w*16 + l15, 8 K-steps) ----
    short8 afr[8];
    #pragma unroll
    for (int ks = 0; ks < 8; ++ks)
        afr[ks] = *(const short8*)&LDS[(w * 16 + l15) * 256 + (((ks * 4 + kq) ^ l15) * 8)];

    float4v sv[8];      // W chunk staging (8 rows/wave, 1KB contiguous each)

    #define ISSUEW(c) do { \
        _Pragma("unroll") \
        for (int u = 0; u < 8; ++u) { \
            const int rr = w * 8 + u;          /* chunk-row 0..63 */ \
            const int ml = rr >> 4, dd = rr & 15; \
            const float* wp = W + ((((size_t)((c) * 4 + ml)) * N_ + n) * D_ + dd) * I_ + lane * 4; \
            GL16(sv[u], wp, 0); \
        } \
    } while (0)

    #define WRITEW(c) do { \
        ushort* buf = &LDS[((c) & 1) * 16384]; \
        _Pragma("unroll") \
        for (int u = 0; u < 8; ++u) { \
            const int rr = w * 8 + u; \
            const int dd = rr & 15; \
            u32x2 h = cvt4(sv[u]); \
            *(u32x2*)&buf[rr * 256 + (((lane >> 1) ^ dd) * 8) + (lane & 1) * 4] = h; \
        } \
    } while (0)

    ISSUEW(0);
    __syncthreads();    // drains afr ds_reads; x region reusable
    VMW0();             // ISSUEW(0) landed   (THE r15 FIX)
    WRITEW(0);
    __syncthreads();    // buf0 visible

    // ---- phase 3: 8 chunks of 4 m ----
    for (int c = 0; c < 8; ++c) {
        if (c < 7) ISSUEW(c + 1);              // in flight across compute(c)
        const ushort* buf = &LDS[(c & 1) * 16384];
        #pragma unroll
        for (int mq = 0; mq < 4; ++mq) {
            const int m = c * 4 + mq;
            f32x4 acc = {0.f, 0.f, 0.f, 0.f};
            #pragma unroll
            for (int ks = 0; ks < 8; ++ks) {
                short8 bf = *(const short8*)&buf[(mq * 16 + l15) * 256 + (((ks * 4 + kq) ^ l15) * 8)];
                acc = __builtin_amdgcn_mfma_f32_16x16x32_bf16(afr[ks], bf, acc, 0, 0, 0);
            }
            // D map: col = lane&15 (=d), row = kq*4 + r (verified)
            #pragma unroll
            for (int r = 0; r < 4; ++r) {
                const int b = w * 16 + kq * 4 + r;
                hat[(((size_t)b * M_ + m) * N_ + n) * D_ + l15] = f2bf(acc[r]);
            }
        }
        if (c < 7) {
            VMW0();            // ISSUEW(c+1) landed (latency hidden by compute)
            WRITEW(c + 1);     // writes buf[(c+1)&1]; its last readers finished
                               // before the previous iteration's barrier
            __syncthreads();   // visible before compute(c+1)
        }
    }
    #undef ISSUEW
    #undef WRITEW
}

// -----------------------------------------------------------------------------
// Kernel 2: dynamic routing (3 iterations), one block per batch element b.
// (r13 version — known-correct, unchanged for clean A/B on the gemm)
// -----------------------------------------------------------------------------
__global__ __launch_bounds__(512) void routing(const ushort* __restrict__ hat,
                                               float* __restrict__ out) {
    __shared__ float blog[M_][N_];
    __shared__ float cmax[N_];
    __shared__ float rcsum[N_];

    const int b    = blockIdx.x;
    const int tid  = threadIdx.x;
    const int lane = tid & 63;
    const int w    = tid >> 6;

    #pragma unroll
    for (int m = 0; m < M_; ++m) blog[m][tid] = 0.f;
    __syncthreads();

    float ov[4][16];
    typedef __attribute__((ext_vector_type(4))) float fl4;

    for (int it = 0; it < 3; ++it) {
        {
            float mx = -3.4e38f;
            #pragma unroll
            for (int m = 0; m < M_; ++m) mx = fmaxf(mx, blog[m][tid]);
            float s = 0.f;
            #pragma unroll
            for (int m = 0; m < M_; ++m) s += __expf(blog[m][tid] - mx);
            cmax[tid]  = mx;
            rcsum[tid] = 1.f / s;
        }
        __syncthreads();

        float sacc[4][16];
        #pragma unroll
        for (int q = 0; q < 4; ++q)
            #pragma unroll
            for (int dd = 0; dd < 16; ++dd) sacc[q][dd] = 0.f;

        for (int r = 0; r < 8; ++r) {
            const int nn = r * 64 + lane;
            #pragma unroll
            for (int q = 0; q < 4; ++q) {
                const int m = w * 4 + q;
                const float cm = __expf(blog[m][nn] - cmax[nn]) * rcsum[nn];
                const size_t base = (((size_t)b * M_ + m) * N_ + nn) * D_;
                short8 h0 = *(const short8*)(hat + base);
                short8 h1 = *(const short8*)(hat + base + 8);
                #pragma unroll
                for (int dd = 0; dd < 8; ++dd) {
                    sacc[q][dd]     += cm * bf2f((ushort)h0[dd]);
                    sacc[q][8 + dd] += cm * bf2f((ushort)h1[dd]);
                }
            }
        }
        #pragma unroll
        for (int off = 32; off >= 1; off >>= 1) {
            #pragma unroll
            for (int q = 0; q < 4; ++q)
                #pragma unroll
                for (int dd = 0; dd < 16; ++dd)
                    sacc[q][dd] += __shfl_xor(sacc[q][dd], off, 64);
        }
        #pragma unroll
        for (int q = 0; q < 4; ++q) {
            float s2 = 0.f;
            #pragma unroll
            for (int dd = 0; dd < 16; ++dd) s2 += sacc[q][dd] * sacc[q][dd];
            const float scale = s2 / (1.f + s2) / sqrtf(s2 + 1e-7f);
            #pragma unroll
            for (int dd = 0; dd < 16; ++dd) ov[q][dd] = scale * sacc[q][dd];
        }

        if (it < 2) {
            for (int r = 0; r < 8; ++r) {
                const int nn = r * 64 + lane;
                #pragma unroll
                for (int q = 0; q < 4; ++q) {
                    const int m = w * 4 + q;
                    const size_t base = (((size_t)b * M_ + m) * N_ + nn) * D_;
                    short8 h0 = *(const short8*)(hat + base);
                    short8 h1 = *(const short8*)(hat + base + 8);
                    float dot = 0.f;
                    #pragma unroll
                    for (int dd = 0; dd < 8; ++dd) {
                        dot += ov[q][dd]     * bf2f((ushort)h0[dd]);
                        dot += ov[q][8 + dd] * bf2f((ushort)h1[dd]);
                    }
                    blog[m][nn] += dot;
                }
            }
        }
        __syncthreads();
    }

    if (lane == 0) {
        #pragma unroll
        for (int q = 0; q < 4; ++q) {
            const int m = w * 4 + q;
            #pragma unroll
            for (int c4 = 0; c4 < 4; ++c4) {
                fl4 v;
                v[0] = ov[q][c4 * 4 + 0];
                v[1] = ov[q][c4 * 4 + 1];
                v[2] = ov[q][c4 * 4 + 2];
                v[3] = ov[q][c4 * 4 + 3];
                *(fl4*)&out[((size_t)b * M_ + m) * D_ + c4 * 4] = v;
            }
        }
    }
}

extern "C" void kernel_launch(void* const* d_in, const int* in_sizes, int n_in,
                              void* d_out, int out_size, void* d_ws, size_t ws_size,
                              hipStream_t stream) {
    const float* x = (const float*)d_in[0];        // [128, 512, 256] fp32
    const float* W = (const float*)d_in[1];        // [32, 512, 16, 256] fp32
    ushort* hat = (ushort*)d_ws;                   // bf16 [128,32,512,16] = 64 MB
    float* out = (float*)d_out;                    // fp32 [128,32,16]

    hat_gemm<<<dim3(N_), dim3(512), 0, stream>>>(x, W, hat);
    routing<<<dim3(B_), dim3(512), 0, stream>>>(hat, out);
}